// Round 6
// baseline (134.779 us; speedup 1.0000x reference)
//
#include <hip/hip_runtime.h>

#define NB 16       // batch
#define NS 512      // tokens
#define ND 384      // hidden dim
#define K4 (ND/4)   // float4s per row = 96
#define CHUNK 128   // output rows per block
#define NT 256      // threads per block (4 waves)

// native 16B vector type — __builtin_nontemporal_store rejects HIP_vector_type
typedef float fx4 __attribute__((ext_vector_type(4)));

// Chunked-persistent fused length-regulator.
// grid = (ceil(L/CHUNK)=32, B=16) = 512 blocks → 2 blocks/CU, 8 waves/CU.
// Each block: one 512-token scan (shfl + wave-combine), one intersect-scatter
// into rowTok[CHUNK], then CHUNK*96 float4 coalesced NONTEMPORAL stores
// (output is write-once; nt keeps 99.5 MB of streamed writes out of L2 so the
// hidden gather working set stays resident).
__global__ __launch_bounds__(NT) void length_regulator_fused(
    const fx4*  __restrict__ hidden4,     // [B*S*96]
    const int*  __restrict__ dur,         // [B*S]
    fx4*        __restrict__ out4,        // [B*L*96]
    float*      __restrict__ outLenF,     // [B], after out4 region
    int L)
{
    const int t = threadIdx.x;
    const int b = blockIdx.y;
    const int j0 = blockIdx.x * CHUNK;

    __shared__ int wsum[NT / 64];
    __shared__ int rowTok[CHUNK];

    // ---- init rowTok to -1 (zero-pad sentinel), CHUNK=128 < NT ----
    if (t < CHUNK) rowTok[t] = -1;

    // ---- scan: 2 durations per thread ----
    int2 d2 = ((const int2*)(dur + b * NS))[t];   // tokens 2t, 2t+1
    int local = d2.x + d2.y;
    int lane = t & 63, wave = t >> 6;
    int x = local;
    #pragma unroll
    for (int off = 1; off < 64; off <<= 1) {
        int y = __shfl_up(x, off, 64);
        if (lane >= off) x += y;
    }
    if (lane == 63) wsum[wave] = x;
    __syncthreads();
    // every thread: prefix of waves below it AND the full batch total
    int wbase = 0, total = 0;
    #pragma unroll
    for (int w = 0; w < NT / 64; ++w) {
        int s = wsum[w];
        if (w < wave) wbase += s;
        total += s;
    }
    int excl = wbase + x - local;                 // exclusive prefix of token 2t

    // ---- intersect-scatter: token s covers rows [excl_s, excl_s + dur_s) ----
    {
        int e0 = excl,        n0 = d2.x;          // token 2t
        int e1 = excl + d2.x, n1 = d2.y;          // token 2t+1
        int lo0 = max(e0, j0), hi0 = min(e0 + n0, j0 + CHUNK);
        for (int j = lo0; j < hi0; ++j) rowTok[j - j0] = 2 * t;
        int lo1 = max(e1, j0), hi1 = min(e1 + n1, j0 + CHUNK);
        for (int j = lo1; j < hi1; ++j) rowTok[j - j0] = 2 * t + 1;
    }
    __syncthreads();

    if (j0 == 0 && t == 0) outLenF[b] = (float)total;

    // ---- gather / store: CHUNK*96 = 12288 float4s, 48 per thread ----
    const size_t outBase = ((size_t)b * L + j0) * K4;
    const size_t hidBase = (size_t)b * NS * K4;
    for (int i = t; i < CHUNK * K4; i += NT) {
        int r = i / K4;                           // const divisor -> magic mul
        int k = i - r * K4;
        if (j0 + r >= L) break;                   // tail chunk guard (r monotonic)
        int g = rowTok[r];
        fx4 v;
        if (g < 0) v = (fx4){0.f, 0.f, 0.f, 0.f};
        else       v = hidden4[hidBase + (size_t)g * K4 + k];
        __builtin_nontemporal_store(v, &out4[outBase + i]);
    }
}

extern "C" void kernel_launch(void* const* d_in, const int* in_sizes, int n_in,
                              void* d_out, int out_size, void* d_ws, size_t ws_size,
                              hipStream_t stream) {
    const float* hidden    = (const float*)d_in[0];
    const int*   durations = (const int*)d_in[1];
    float* out = (float*)d_out;

    // out_size = B*L*D + B
    int L = (out_size - NB) / (NB * ND);
    float* outLenF = out + (size_t)NB * L * ND;

    dim3 grid((L + CHUNK - 1) / CHUNK, NB);
    length_regulator_fused<<<grid, NT, 0, stream>>>(
        (const fx4*)hidden, durations, (fx4*)out, outLenF, L);
}

// Round 7
// 118.815 us; speedup vs baseline: 1.1344x; 1.1344x over previous
//
#include <hip/hip_runtime.h>

#define NB 16      // batch
#define NS 512     // tokens
#define ND 384     // hidden dim
#define K4 (ND/4)  // float4s per row = 96
#define ROWS 16    // output rows per block (best measured: R2)
#define NT 256     // threads per block (4 waves)

// Fused length-regulator, R2 shape + parallel intersect-scatter (no binary
// search, no csum LDS materialization; 2 barriers instead of 4).
// Each block: (batch b, window of ROWS output rows).
//  1. 256 threads load the batch's 512 durations (int2 each, L2-hot),
//     shfl-scan + wave-combine (every thread sums the 4 wave totals).
//  2. Intersect-scatter: each thread clips its 2 tokens' output ranges
//     [excl, excl+dur) against the window [j0, j0+ROWS) -> rowTok[].
//  3. 256 threads gather/store ROWS*96 = 1536 float4s, fully coalesced.
// Window-0 blocks also write out_lengths[b] as float (harness reads flat f32).
__global__ __launch_bounds__(NT) void length_regulator_fused(
    const float4* __restrict__ hidden4,   // [B*S*96]
    const int*    __restrict__ dur,       // [B*S]
    float4*       __restrict__ out4,      // [B*L*96]
    float*        __restrict__ outLenF,   // [B], after out4 region
    int L)
{
    const int t = threadIdx.x;
    const int b = blockIdx.y;
    const int j0 = blockIdx.x * ROWS;

    __shared__ int wsum[NT / 64];
    __shared__ int rowTok[ROWS];

    // ---- init rowTok to -1 (zero-pad sentinel) ----
    if (t < ROWS) rowTok[t] = -1;

    // ---- scan: 2 durations per thread ----
    int2 d2 = ((const int2*)(dur + b * NS))[t];   // tokens 2t, 2t+1
    int local = d2.x + d2.y;
    int lane = t & 63, wave = t >> 6;
    int x = local;
    #pragma unroll
    for (int off = 1; off < 64; off <<= 1) {
        int y = __shfl_up(x, off, 64);
        if (lane >= off) x += y;
    }
    if (lane == 63) wsum[wave] = x;
    __syncthreads();
    // every thread: prefix of waves below it AND the full batch total
    int wbase = 0, total = 0;
    #pragma unroll
    for (int w = 0; w < NT / 64; ++w) {
        int s = wsum[w];
        if (w < wave) wbase += s;
        total += s;
    }
    int excl = wbase + x - local;                 // exclusive prefix of token 2t

    // ---- intersect-scatter: token s covers rows [excl_s, excl_s + dur_s) ----
    {
        int e0 = excl,        n0 = d2.x;          // token 2t
        int e1 = excl + d2.x, n1 = d2.y;          // token 2t+1
        int lo0 = max(e0, j0), hi0 = min(e0 + n0, j0 + ROWS);
        for (int j = lo0; j < hi0; ++j) rowTok[j - j0] = 2 * t;
        int lo1 = max(e1, j0), hi1 = min(e1 + n1, j0 + ROWS);
        for (int j = lo1; j < hi1; ++j) rowTok[j - j0] = 2 * t + 1;
    }
    __syncthreads();

    if (j0 == 0 && t == 0) outLenF[b] = (float)total;

    // ---- gather / store: ROWS*96 = 1536 float4s, 6 per thread, coalesced ----
    const size_t outBase = ((size_t)b * L + j0) * K4;
    const size_t hidBase = (size_t)b * NS * K4;
    #pragma unroll
    for (int i = t; i < ROWS * K4; i += NT) {
        int r = i / K4;                           // const divisor -> magic mul
        int k = i - r * K4;
        if (j0 + r >= L) break;                   // tail window guard (r monotonic)
        int g = rowTok[r];
        float4 v;
        if (g < 0) v = make_float4(0.f, 0.f, 0.f, 0.f);
        else       v = hidden4[hidBase + (size_t)g * K4 + k];
        out4[outBase + i] = v;
    }
}

extern "C" void kernel_launch(void* const* d_in, const int* in_sizes, int n_in,
                              void* d_out, int out_size, void* d_ws, size_t ws_size,
                              hipStream_t stream) {
    const float* hidden    = (const float*)d_in[0];
    const int*   durations = (const int*)d_in[1];
    float* out = (float*)d_out;

    // out_size = B*L*D + B
    int L = (out_size - NB) / (NB * ND);
    float* outLenF = out + (size_t)NB * L * ND;

    dim3 grid((L + ROWS - 1) / ROWS, NB);
    length_regulator_fused<<<grid, NT, 0, stream>>>(
        (const float4*)hidden, durations, (float4*)out, outLenF, L);
}